// Round 5
// baseline (146.220 us; speedup 1.0000x reference)
//
#include <hip/hip_runtime.h>
#include <hip/hip_bf16.h>

// B=4, T=2048, SD=64, NE=4096, H=8, HS=8, FH=256. All reference reshapes are
// flat reinterpretations -> one flat buffer serves every "view".
// h/y/e flat element (t,l): b*131072 + t*64 + l.
// x viewed (B,SD,SD,T): b*4194304 + i*131072 + j*2048 + t.
// out viewed (B,SD,SD,T): b*8388608 + i*131072 + j*2048 + t.
// Softmax: shift-invariant; fixed offset exp(qc-40) -> no global-max pass.

#define EPSF 1e-5f
#define OFFS 40.0f

// ------ K1: Feebler + LayerNorm1 + per-block column partial sums ------------
__global__ void K1(const float* __restrict__ x, const float* __restrict__ fw,
                   const float* __restrict__ g, const float* __restrict__ bia,
                   float* __restrict__ h, float* __restrict__ y,
                   float* __restrict__ part) {
    int xb = blockIdx.x;
    int b = xb & 3, i = xb >> 2;                // b-fast: fw panel shared in L2
    int t4 = blockIdx.y * 256 + threadIdx.x;    // float4 idx 0..511 in (b,i)
    const float4* x4 = (const float4*)x + (size_t)b * 2097152 + (size_t)i * 32768 + t4;
    const float4* f4 = (const float4*)fw + (size_t)i * 32768 + t4;
    float4 acc = make_float4(0.f, 0.f, 0.f, 0.f);
    #pragma unroll 8
    for (int j = 0; j < 64; ++j) {
        float4 xv = x4[(size_t)j * 512];
        float4 fv = f4[(size_t)j * 512];
        acc.x += xv.x * fv.x; acc.y += xv.y * fv.y;
        acc.z += xv.z * fv.z; acc.w += xv.w * fv.w;
    }
    float s1 = acc.x + acc.y + acc.z + acc.w;
    float s2 = acc.x * acc.x + acc.y * acc.y + acc.z * acc.z + acc.w * acc.w;
    for (int off = 8; off; off >>= 1) {
        s1 += __shfl_xor(s1, off);
        s2 += __shfl_xor(s2, off);
    }
    float m = s1 * (1.f / 64.f);
    float var = s2 * (1.f / 64.f) - m * m;
    float rs = rsqrtf(var + EPSF);
    float4 gv = ((const float4*)g)[t4 & 15];
    float4 bv = ((const float4*)bia)[t4 & 15];
    float4 yv;
    yv.x = (acc.x - m) * rs * gv.x + bv.x;
    yv.y = (acc.y - m) * rs * gv.y + bv.y;
    yv.z = (acc.z - m) * rs * gv.z + bv.z;
    yv.w = (acc.w - m) * rs * gv.w + bv.w;
    size_t oidx = (size_t)b * 32768 + (size_t)i * 512 + t4;
    ((float4*)h)[oidx] = acc;
    ((float4*)y)[oidx] = yv;
    __shared__ float ysL[64];
    if (threadIdx.x < 64) ysL[threadIdx.x] = 0.f;
    __syncthreads();
    int c0 = (t4 & 15) * 4;
    atomicAdd(&ysL[c0 + 0], yv.x);
    atomicAdd(&ysL[c0 + 1], yv.y);
    atomicAdd(&ysL[c0 + 2], yv.z);
    atomicAdd(&ysL[c0 + 3], yv.w);
    __syncthreads();
    if (threadIdx.x < 64)
        part[(blockIdx.y * 256 + xb) * 64 + threadIdx.x] = ysL[threadIdx.x];
}

// ------ K1r: reduce partials -> ysum; ck = ysum@Wk, cv = ysum@Wv ------------
__global__ void K1r(const float* __restrict__ part, const float* __restrict__ wk,
                    const float* __restrict__ wv, float* __restrict__ ck,
                    float* __restrict__ cv) {
    __shared__ float ysL[256];
    int tid = threadIdx.x;
    int b = tid >> 6, c = tid & 63;
    float s = 0.f;
    for (int k = 0; k < 128; ++k) {
        int i = k & 63, yy = k >> 6;
        s += part[(yy * 256 + i * 4 + b) * 64 + c];
    }
    ysL[tid] = s;
    __syncthreads();
    int hh = c >> 3, d = c & 7;
    float a = 0.f, e = 0.f;
    for (int sdx = 0; sdx < 64; ++sdx) {
        float ys = ysL[b * 64 + sdx];
        a += ys * wk[hh * 512 + sdx * 8 + d];
        e += ys * wv[hh * 512 + sdx * 8 + d];
    }
    ck[tid] = a;
    cv[tid] = e;
}

// ------ K2: e = exp((y@Wq)*ck - OFFS), per-tile column expsum partials ------
__global__ void K2(const float* __restrict__ y, const float* __restrict__ wq,
                   const float* __restrict__ ck, float* __restrict__ e,
                   float* __restrict__ esum) {
    __shared__ float yT[64][20];
    __shared__ float wqL[64][64];
    __shared__ float psum[4][64];
    int b = blockIdx.x, tile = blockIdx.y, t0 = tile * 16;
    int tid = threadIdx.x;
    for (int k = 0; k < 4; ++k) {
        int idx = k * 256 + tid;
        int r = idx >> 6, s = idx & 63;
        yT[s][r] = y[(size_t)b * 131072 + (size_t)(t0 + r) * 64 + s];
    }
    for (int k = 0; k < 16; ++k) {
        int idx = k * 256 + tid;
        int r = idx >> 6, cc = idx & 63;
        wqL[r][cc] = wq[(cc >> 3) * 512 + r * 8 + (cc & 7)];
    }
    __syncthreads();
    int c = tid & 63, tq = tid >> 6;
    float ckc = ck[b * 64 + c];
    float acc[4] = {0.f, 0.f, 0.f, 0.f};
    for (int s = 0; s < 64; ++s) {
        float w = wqL[s][c];
        float4 a0 = *(const float4*)&yT[s][tq * 4];
        acc[0] += a0.x * w; acc[1] += a0.y * w;
        acc[2] += a0.z * w; acc[3] += a0.w * w;
    }
    float ls = 0.f;
    #pragma unroll
    for (int k = 0; k < 4; ++k) {
        float v = __expf(acc[k] * ckc - OFFS);
        e[(size_t)b * 131072 + (size_t)(t0 + tq * 4 + k) * 64 + c] = v;
        ls += v;
    }
    psum[tq][c] = ls;
    __syncthreads();
    if (tid < 64)
        esum[(b * 128 + tile) * 64 + tid] =
            psum[0][tid] + psum[1][tid] + psum[2][tid] + psum[3][tid];
}

// ------ K2r: scl[b][l] = cv / sum_tiles esum (tiny) -------------------------
__global__ void K2r(const float* __restrict__ esum, const float* __restrict__ cv,
                    float* __restrict__ scl) {
    int tid = threadIdx.x;          // 256 = B*64
    int b = tid >> 6, l = tid & 63;
    float s = 0.f;
    for (int t = 0; t < 128; ++t) s += esum[(b * 128 + t) * 64 + l];
    scl[tid] = cv[tid] / s;
}

// ------ K4: proj+LN2+FFN (LDS-staged weights) + fused Booster -> out --------
// Block (b fast, chunk 0..255): 8 t-rows = flat range [chunk*512,+512).
// LDS 40KB -> 4 blocks/CU. Weights staged per block (L2 traffic /4 waves).
__global__ void __launch_bounds__(256, 4)
K4(const float* __restrict__ h, const float* __restrict__ e,
   const float* __restrict__ scl, const float* __restrict__ projw,
   const float* __restrict__ projb, const float* __restrict__ g2,
   const float* __restrict__ b2l, const float* __restrict__ w1,
   const float* __restrict__ b1, const float* __restrict__ w2,
   const float* __restrict__ fb2, const float* __restrict__ bw,
   float* __restrict__ out) {
    __shared__ float bufA[4096];     // projw, then w1 chunk [s][j]
    __shared__ float bufB[4096];     // w2 chunk [j][l]
    __shared__ float2 pT[4][64];
    __shared__ float2 y2T[4][64];
    __shared__ float2 hidT[4][64];
    __shared__ float hfL[512];
    int b = blockIdx.x, chunk = blockIdx.y;
    int tid = threadIdx.x, l = tid & 63, w = tid >> 6;

    // stage projw (16KB)
    #pragma unroll
    for (int k = 0; k < 16; ++k) bufA[k * 256 + tid] = projw[k * 256 + tid];

    float sc = scl[b * 64 + l];
    size_t base = (size_t)b * 131072 + (size_t)(chunk * 8 + w * 2) * 64 + l;
    float2 p;
    p.x = e[base] * sc;
    p.y = e[base + 64] * sc;
    pT[w][l] = p;
    float h0 = h[base], hh1 = h[base + 64];
    __syncthreads();

    // proj from LDS
    float a0 = 0.f, a1 = 0.f;
    for (int c = 0; c < 64; ++c) {
        float2 pv = pT[w][c];
        float pw = bufA[c * 64 + l];
        a0 += pv.x * pw; a1 += pv.y * pw;
    }
    float pb = projb[l], g2v = g2[l], b2v = b2l[l];
    float hmid[2], y2[2];
    hmid[0] = h0 + a0 + pb;
    hmid[1] = hh1 + a1 + pb;
    #pragma unroll
    for (int rr = 0; rr < 2; ++rr) {
        float v = hmid[rr];
        float s1 = v, s2 = v * v;
        for (int off = 32; off; off >>= 1) {
            s1 += __shfl_xor(s1, off);
            s2 += __shfl_xor(s2, off);
        }
        float mm = s1 * (1.f / 64.f);
        float var = s2 * (1.f / 64.f) - mm * mm;
        float rs = rsqrtf(var + EPSF);
        y2[rr] = (v - mm) * rs * g2v + b2v;
    }
    y2T[w][l] = make_float2(y2[0], y2[1]);
    __syncthreads();   // proj done reading bufA; y2T visible

    // FFN in 4 chunks of 64 hidden units; weights staged in LDS
    float a2_0 = 0.f, a2_1 = 0.f;
    for (int c4 = 0; c4 < 4; ++c4) {
        #pragma unroll
        for (int k = 0; k < 16; ++k) {
            int idx = k * 256 + tid;
            int r = idx >> 6, jc = idx & 63;
            bufA[idx] = w1[r * 256 + c4 * 64 + jc];        // w1c[s][j]
            bufB[idx] = w2[(c4 * 64 + r) * 64 + jc];       // w2c[j][l]
        }
        __syncthreads();
        // FFN1: hidden unit (c4*64+l) for this wave's 2 rows
        float bb = b1[c4 * 64 + l];
        float hc0 = bb, hc1 = bb;
        for (int s = 0; s < 64; ++s) {
            float2 yv = y2T[w][s];
            float w1v = bufA[s * 64 + l];
            hc0 += yv.x * w1v;
            hc1 += yv.y * w1v;
        }
        hidT[w][l] = make_float2(fmaxf(hc0, 0.f), fmaxf(hc1, 0.f));
        // FFN2 partial over this chunk (same-wave LDS, no barrier needed)
        for (int j = 0; j < 64; ++j) {
            float2 hv = hidT[w][j];
            float w2v = bufB[j * 64 + l];
            a2_0 += hv.x * w2v;
            a2_1 += hv.y * w2v;
        }
        __syncthreads();   // protect bufA/bufB for next chunk
    }
    float fb = fb2[l];
    hfL[(w * 2 + 0) * 64 + l] = hmid[0] + a2_0 + fb;
    hfL[(w * 2 + 1) * 64 + l] = hmid[1] + a2_1 + fb;
    __syncthreads();

    // Booster: flat chunk -> (j, t-range); out[b,i,j,tr] = bw[i,j,tr] * hfL
    int jj = chunk >> 2;
    int tq4 = (chunk & 3) * 128;
    int f4 = tid & 127, ig = tid >> 7;
    float4 hv = *(const float4*)&hfL[f4 * 4];
    const float4* bwp = (const float4*)bw + (size_t)jj * 512 + tq4 + f4;
    float4* op = (float4*)out + (size_t)b * 2097152 + (size_t)jj * 512 + tq4 + f4;
    for (int it = 0; it < 32; ++it) {
        int i = it * 2 + ig;
        float4 wv = bwp[(size_t)i * 32768];
        float4 ov;
        ov.x = wv.x * hv.x; ov.y = wv.y * hv.y;
        ov.z = wv.z * hv.z; ov.w = wv.w * hv.w;
        op[(size_t)i * 32768] = ov;
    }
}

extern "C" void kernel_launch(void* const* d_in, const int* in_sizes, int n_in,
                              void* d_out, int out_size, void* d_ws, size_t ws_size,
                              hipStream_t stream) {
    const float* x     = (const float*)d_in[0];
    const float* fw    = (const float*)d_in[1];
    const float* bw    = (const float*)d_in[2];
    const float* wq    = (const float*)d_in[3];
    const float* wk    = (const float*)d_in[4];
    const float* wv    = (const float*)d_in[5];
    const float* projw = (const float*)d_in[6];
    const float* projb = (const float*)d_in[7];
    const float* g1    = (const float*)d_in[8];
    const float* b1l   = (const float*)d_in[9];
    const float* g2    = (const float*)d_in[10];
    const float* b2l   = (const float*)d_in[11];
    const float* w1    = (const float*)d_in[12];
    const float* b1    = (const float*)d_in[13];
    const float* w2    = (const float*)d_in[14];
    const float* b2    = (const float*)d_in[15];
    float* out = (float*)d_out;

    float* wsf = (float*)d_ws;
    float* h    = wsf;                 // 524288
    float* y    = wsf + 524288;        // 524288
    float* e    = wsf + 1048576;       // 524288
    float* part = wsf + 1572864;       // 32768
    float* esum = wsf + 1605632;       // 32768
    float* ck   = wsf + 1638400;       // 256
    float* cvb  = wsf + 1638656;       // 256
    float* scl  = wsf + 1638912;       // 256

    K1 <<<dim3(256, 2), 256, 0, stream>>>(x, fw, g1, b1l, h, y, part);
    K1r<<<1, 256, 0, stream>>>(part, wk, wv, ck, cvb);
    K2 <<<dim3(4, 128), 256, 0, stream>>>(y, wq, ck, e, esum);
    K2r<<<1, 256, 0, stream>>>(esum, cvb, scl);
    K4 <<<dim3(4, 256), 256, 0, stream>>>(h, e, scl, projw, projb,
                                          g2, b2l, w1, b1, w2, b2, bw, out);
}

// Round 6
// 137.450 us; speedup vs baseline: 1.0638x; 1.0638x over previous
//
#include <hip/hip_runtime.h>
#include <hip/hip_bf16.h>

// B=4, T=2048, SD=64, NE=4096, H=8, HS=8, FH=256. All reference reshapes are
// flat reinterpretations -> one flat buffer serves every "view".
// h/y/e/hf flat element (t,l): b*131072 + t*64 + l.
// x viewed (B,SD,SD,T): b*4194304 + i*131072 + j*2048 + t.
// out viewed (B,SD,SD,T): b*8388608 + i*131072 + j*2048 + t.
// Softmax: shift-invariant; fixed offset exp(qc-40) -> no global-max pass.

#define EPSF 1e-5f
#define OFFS 40.0f

// ------ K1: Feebler + LayerNorm1 + per-block column partial sums ------------
// 512 blocks, XCD-swizzled so the 4 b-blocks of one fw panel land on ONE XCD:
// bid = xcd + 8*slot; b = slot&3; panel = (slot>>2)*8 + xcd; i=panel&63.
__global__ void K1(const float* __restrict__ x, const float* __restrict__ fw,
                   const float* __restrict__ g, const float* __restrict__ bia,
                   float* __restrict__ h, float* __restrict__ y,
                   float* __restrict__ part) {
    int bid = blockIdx.x;
    int xcd = bid & 7, slot = bid >> 3;
    int b = slot & 3;
    int panel = (slot >> 2) * 8 + xcd;          // 0..127 = chunk*64 + i
    int i = panel & 63, chunk = panel >> 6;
    int t4 = chunk * 256 + threadIdx.x;         // float4 idx 0..511 in (b,i)
    const float4* x4 = (const float4*)x + (size_t)b * 2097152 + (size_t)i * 32768 + t4;
    const float4* f4 = (const float4*)fw + (size_t)i * 32768 + t4;
    float4 acc = make_float4(0.f, 0.f, 0.f, 0.f);
    #pragma unroll 8
    for (int j = 0; j < 64; ++j) {
        float4 xv = x4[(size_t)j * 512];
        float4 fv = f4[(size_t)j * 512];
        acc.x += xv.x * fv.x; acc.y += xv.y * fv.y;
        acc.z += xv.z * fv.z; acc.w += xv.w * fv.w;
    }
    float s1 = acc.x + acc.y + acc.z + acc.w;
    float s2 = acc.x * acc.x + acc.y * acc.y + acc.z * acc.z + acc.w * acc.w;
    for (int off = 8; off; off >>= 1) {
        s1 += __shfl_xor(s1, off);
        s2 += __shfl_xor(s2, off);
    }
    float m = s1 * (1.f / 64.f);
    float var = s2 * (1.f / 64.f) - m * m;
    float rs = rsqrtf(var + EPSF);
    float4 gv = ((const float4*)g)[t4 & 15];
    float4 bv = ((const float4*)bia)[t4 & 15];
    float4 yv;
    yv.x = (acc.x - m) * rs * gv.x + bv.x;
    yv.y = (acc.y - m) * rs * gv.y + bv.y;
    yv.z = (acc.z - m) * rs * gv.z + bv.z;
    yv.w = (acc.w - m) * rs * gv.w + bv.w;
    size_t oidx = (size_t)b * 32768 + (size_t)i * 512 + t4;
    ((float4*)h)[oidx] = acc;
    ((float4*)y)[oidx] = yv;
    __shared__ float ysL[64];
    if (threadIdx.x < 64) ysL[threadIdx.x] = 0.f;
    __syncthreads();
    int c0 = (t4 & 15) * 4;
    atomicAdd(&ysL[c0 + 0], yv.x);
    atomicAdd(&ysL[c0 + 1], yv.y);
    atomicAdd(&ysL[c0 + 2], yv.z);
    atomicAdd(&ysL[c0 + 3], yv.w);
    __syncthreads();
    if (threadIdx.x < 64)
        part[(panel * 4 + b) * 64 + threadIdx.x] = ysL[threadIdx.x];
}

// ------ K2: inline ck from part; e = exp((y@Wq)*ck - OFFS); esum partials ---
__global__ void K2(const float* __restrict__ y, const float* __restrict__ wq,
                   const float* __restrict__ wk, const float* __restrict__ part,
                   float* __restrict__ e, float* __restrict__ esum) {
    __shared__ float yT[64][20];
    __shared__ float wqL[64][64];
    __shared__ float psum[4][64];
    __shared__ float psA[4][64];
    __shared__ float ysL[64];
    int b = blockIdx.x, tile = blockIdx.y, t0 = tile * 16;
    int tid = threadIdx.x;
    int c = tid & 63, grp = tid >> 6;
    // reduce part -> ysum (this block's b)
    float sA = 0.f;
    for (int pp = 0; pp < 32; ++pp)
        sA += part[((grp * 32 + pp) * 4 + b) * 64 + c];
    psA[grp][c] = sA;
    for (int k = 0; k < 4; ++k) {
        int idx = k * 256 + tid;
        int r = idx >> 6, s = idx & 63;
        yT[s][r] = y[(size_t)b * 131072 + (size_t)(t0 + r) * 64 + s];
    }
    for (int k = 0; k < 16; ++k) {
        int idx = k * 256 + tid;
        int r = idx >> 6, cc = idx & 63;
        wqL[r][cc] = wq[(cc >> 3) * 512 + r * 8 + (cc & 7)];
    }
    __syncthreads();
    if (tid < 64)
        ysL[tid] = psA[0][tid] + psA[1][tid] + psA[2][tid] + psA[3][tid];
    __syncthreads();
    // ck for column c (4x redundant across grp, cheap)
    float ckc = 0.f;
    for (int s = 0; s < 64; ++s)
        ckc += ysL[s] * wk[(c >> 3) * 512 + s * 8 + (c & 7)];
    float acc[4] = {0.f, 0.f, 0.f, 0.f};
    for (int s = 0; s < 64; ++s) {
        float w = wqL[s][c];
        float4 a0 = *(const float4*)&yT[s][grp * 4];
        acc[0] += a0.x * w; acc[1] += a0.y * w;
        acc[2] += a0.z * w; acc[3] += a0.w * w;
    }
    float ls = 0.f;
    #pragma unroll
    for (int k = 0; k < 4; ++k) {
        float v = __expf(acc[k] * ckc - OFFS);
        e[(size_t)b * 131072 + (size_t)(t0 + grp * 4 + k) * 64 + c] = v;
        ls += v;
    }
    psum[grp][c] = ls;
    __syncthreads();
    if (tid < 64)
        esum[(b * 128 + tile) * 64 + tid] =
            psum[0][tid] + psum[1][tid] + psum[2][tid] + psum[3][tid];
}

// ------ K3m: inline cv/scl; proj+LN2+FFN (LDS weights) -> hf ----------------
// Block (b, chunk of 16 rows): 4 waves x 4 rows. ~46KB LDS -> 3 blocks/CU.
__global__ void __launch_bounds__(256, 3)
K3m(const float* __restrict__ h, const float* __restrict__ e,
    const float* __restrict__ part, const float* __restrict__ esum,
    const float* __restrict__ wv, const float* __restrict__ projw,
    const float* __restrict__ projb, const float* __restrict__ g2,
    const float* __restrict__ b2l, const float* __restrict__ w1,
    const float* __restrict__ b1, const float* __restrict__ w2,
    const float* __restrict__ fb2, float* __restrict__ hf) {
    __shared__ float bufA[4096];      // projw, then w1 chunk [s][j]
    __shared__ float bufB[4096];      // w2 chunk [j][l]
    __shared__ float4 pT[4][64];
    __shared__ float4 y2T[4][64];
    __shared__ float4 hidT[4][64];
    __shared__ float psA[4][64], psE[4][64];
    __shared__ float ysL[64], denL[64];
    int b = blockIdx.x, chunk = blockIdx.y;
    int tid = threadIdx.x, l = tid & 63, w = tid >> 6;

    // stage projw
    float4* bufA4 = (float4*)bufA;
    const float4* pw4 = (const float4*)projw;
    #pragma unroll
    for (int k = 0; k < 4; ++k) bufA4[k * 256 + tid] = pw4[k * 256 + tid];
    // partial reduces for ysum (->cv) and den
    float sA = 0.f, sE = 0.f;
    for (int pp = 0; pp < 32; ++pp) {
        sA += part[((w * 32 + pp) * 4 + b) * 64 + l];
        sE += esum[(b * 128 + w * 32 + pp) * 64 + l];
    }
    psA[w][l] = sA;
    psE[w][l] = sE;
    __syncthreads();
    if (tid < 64) {
        ysL[tid] = psA[0][tid] + psA[1][tid] + psA[2][tid] + psA[3][tid];
        denL[tid] = psE[0][tid] + psE[1][tid] + psE[2][tid] + psE[3][tid];
    }
    __syncthreads();
    float cvv = 0.f;
    for (int s = 0; s < 64; ++s)
        cvv += ysL[s] * wv[(l >> 3) * 512 + s * 8 + (l & 7)];
    float sc = cvv / denL[l];

    size_t base = (size_t)b * 131072 + (size_t)(chunk * 16 + w * 4) * 64 + l;
    float4 p;
    p.x = e[base] * sc;
    p.y = e[base + 64] * sc;
    p.z = e[base + 128] * sc;
    p.w = e[base + 192] * sc;
    pT[w][l] = p;
    float h0 = h[base], h1r = h[base + 64], h2r = h[base + 128], h3r = h[base + 192];
    __syncthreads();

    // proj from LDS
    float a[4] = {0.f, 0.f, 0.f, 0.f};
    for (int c = 0; c < 64; ++c) {
        float4 pv = pT[w][c];
        float pw = bufA[c * 64 + l];
        a[0] += pv.x * pw; a[1] += pv.y * pw;
        a[2] += pv.z * pw; a[3] += pv.w * pw;
    }
    float pb = projb[l], g2v = g2[l], b2v = b2l[l];
    float hmid[4] = {h0 + a[0] + pb, h1r + a[1] + pb, h2r + a[2] + pb, h3r + a[3] + pb};
    float y2[4];
    #pragma unroll
    for (int rr = 0; rr < 4; ++rr) {
        float v = hmid[rr];
        float s1 = v, s2 = v * v;
        for (int off = 32; off; off >>= 1) {
            s1 += __shfl_xor(s1, off);
            s2 += __shfl_xor(s2, off);
        }
        float mm = s1 * (1.f / 64.f);
        float var = s2 * (1.f / 64.f) - mm * mm;
        float rs = rsqrtf(var + EPSF);
        y2[rr] = (v - mm) * rs * g2v + b2v;
    }
    y2T[w][l] = make_float4(y2[0], y2[1], y2[2], y2[3]);
    __syncthreads();   // proj done with bufA; y2T visible

    // FFN in 4 chunks of 64 hidden units
    float4* bufB4 = (float4*)bufB;
    const float4* w14 = (const float4*)w1;
    const float4* w24 = (const float4*)w2;
    float a2[4] = {0.f, 0.f, 0.f, 0.f};
    for (int c4 = 0; c4 < 4; ++c4) {
        #pragma unroll
        for (int k = 0; k < 4; ++k) {
            int f = k * 256 + tid;
            int r = f >> 4, q = f & 15;
            bufA4[r * 16 + q] = w14[r * 64 + c4 * 16 + q];          // w1c[s][j]
            bufB4[r * 16 + q] = w24[(size_t)(c4 * 64 + r) * 16 + q]; // w2c[j][l]
        }
        __syncthreads();
        float bb = b1[c4 * 64 + l];
        float hc[4] = {bb, bb, bb, bb};
        for (int s = 0; s < 64; ++s) {
            float4 yv = y2T[w][s];
            float w1v = bufA[s * 64 + l];
            hc[0] += yv.x * w1v; hc[1] += yv.y * w1v;
            hc[2] += yv.z * w1v; hc[3] += yv.w * w1v;
        }
        hidT[w][l] = make_float4(fmaxf(hc[0], 0.f), fmaxf(hc[1], 0.f),
                                 fmaxf(hc[2], 0.f), fmaxf(hc[3], 0.f));
        for (int j = 0; j < 64; ++j) {
            float4 hv = hidT[w][j];
            float w2v = bufB[j * 64 + l];
            a2[0] += hv.x * w2v; a2[1] += hv.y * w2v;
            a2[2] += hv.z * w2v; a2[3] += hv.w * w2v;
        }
        __syncthreads();   // protect bufA/bufB for next chunk
    }
    float fb = fb2[l];
    hf[base]       = hmid[0] + a2[0] + fb;
    hf[base + 64]  = hmid[1] + a2[1] + fb;
    hf[base + 128] = hmid[2] + a2[2] + fb;
    hf[base + 192] = hmid[3] + a2[3] + fb;
}

// ------ K5: Booster. out[b,i,j,t'] = bw[i,j,t'] * hf[b, j*2048+t'] ----------
// Each bw float4 read by exactly one thread; loop b inside (hf L2/L3-resident).
__global__ void K5(const float* __restrict__ hf, const float* __restrict__ bw,
                   float* __restrict__ out) {
    int wi = blockIdx.x * 256 + threadIdx.x;    // 0 .. 2M-1 float4 index into bw
    int i = wi >> 15;
    int jt = wi & 32767;                        // j*512 + t4
    const float4* bw4 = (const float4*)bw;
    const float4* hf4 = (const float4*)hf;
    float4* o4 = (float4*)out;
    float4 wv = bw4[wi];
    size_t obase = (size_t)i * 32768 + jt;
    #pragma unroll
    for (int b = 0; b < 4; ++b) {
        float4 hv = hf4[b * 32768 + jt];
        float4 ov;
        ov.x = wv.x * hv.x; ov.y = wv.y * hv.y;
        ov.z = wv.z * hv.z; ov.w = wv.w * hv.w;
        o4[(size_t)b * 2097152 + obase] = ov;
    }
}

extern "C" void kernel_launch(void* const* d_in, const int* in_sizes, int n_in,
                              void* d_out, int out_size, void* d_ws, size_t ws_size,
                              hipStream_t stream) {
    const float* x     = (const float*)d_in[0];
    const float* fw    = (const float*)d_in[1];
    const float* bw    = (const float*)d_in[2];
    const float* wq    = (const float*)d_in[3];
    const float* wk    = (const float*)d_in[4];
    const float* wv    = (const float*)d_in[5];
    const float* projw = (const float*)d_in[6];
    const float* projb = (const float*)d_in[7];
    const float* g1    = (const float*)d_in[8];
    const float* b1l   = (const float*)d_in[9];
    const float* g2    = (const float*)d_in[10];
    const float* b2l   = (const float*)d_in[11];
    const float* w1    = (const float*)d_in[12];
    const float* b1    = (const float*)d_in[13];
    const float* w2    = (const float*)d_in[14];
    const float* b2    = (const float*)d_in[15];
    float* out = (float*)d_out;

    float* wsf = (float*)d_ws;
    float* h    = wsf;                 // 524288
    float* y    = wsf + 524288;        // 524288 (reused as hf after K2)
    float* hf   = wsf + 524288;        //   - y dead after K2; hf live K3m->K5
    float* e    = wsf + 1048576;       // 524288
    float* part = wsf + 1572864;       // 32768
    float* esum = wsf + 1605632;       // 32768

    K1 <<<512, 256, 0, stream>>>(x, fw, g1, b1l, h, y, part);
    K2 <<<dim3(4, 128), 256, 0, stream>>>(y, wq, wk, part, e, esum);
    K3m<<<dim3(4, 128), 256, 0, stream>>>(h, e, part, esum, wv, projw, projb,
                                          g2, b2l, w1, b1, w2, b2, hf);
    K5 <<<8192, 256, 0, stream>>>(hf, bw, out);
}